// Round 8
// baseline (50.125 us; speedup 1.0000x reference)
//
#include <hip/hip_runtime.h>

#define BSZ 2048
#define DIM 256

typedef float f4 __attribute__((ext_vector_type(4)));

// One block per graph. 256 threads = 4 waves; all 2048 blocks co-resident.
// R6: contiguous per-wave row streams (1KB sequential per wave) 50->48us.
// R7: NT on first 1/8 of blocks 48->45.9us.
// R8 experiment: FULL NT on the contiguous pattern. R4's "NT hurts" was
// confounded with the old strided pattern; within the contiguous pattern
// NT has only helped. Discriminates L3-retention vs allocation-overhead.
__global__ __launch_bounds__(256) void graph_mean_kernel(
    const float* __restrict__ emb,
    const int*   __restrict__ len,
    float*       __restrict__ out)
{
    const int b    = blockIdx.x;
    const int tid  = threadIdx.x;
    const int lane = tid & 63;
    const int wv   = tid >> 6;

    // ---- Phase 1: offset = sum len[0..b), plus global max(len) ----
    int po = 0, pm = 0;
    #pragma unroll
    for (int j = 0; j < 8; ++j) {
        const int i = tid + j * 256;
        const int l = len[i];
        po += (i < b) ? l : 0;
        pm  = max(pm, l);
    }
    #pragma unroll
    for (int d = 32; d > 0; d >>= 1) {
        po += __shfl_down(po, d);
        pm  = max(pm, __shfl_down(pm, d));
    }
    __shared__ int s_o[4];
    __shared__ int s_m[4];
    if (lane == 0) { s_o[wv] = po; s_m[wv] = pm; }
    __syncthreads();
    const int   start   = s_o[0] + s_o[1] + s_o[2] + s_o[3];
    const float inv_max = 1.0f / (float)max(max(s_m[0], s_m[1]), max(s_m[2], s_m[3]));
    const int   mylen   = len[b];

    // ---- Phase 2: segment sum. Wave wv owns rows [lo, hi) contiguous. ----
    const int lo = (mylen *  wv     ) >> 2;
    const int hi = (mylen * (wv + 1)) >> 2;

    f4 acc0 = {0.f, 0.f, 0.f, 0.f};
    f4 acc1 = {0.f, 0.f, 0.f, 0.f};
    f4 acc2 = {0.f, 0.f, 0.f, 0.f};
    f4 acc3 = {0.f, 0.f, 0.f, 0.f};
    const f4* base = reinterpret_cast<const f4*>(emb) + lane;   // lane = cols lane*4..+3
    int r = lo;
    for (; r + 4 <= hi; r += 4) {
        const size_t row0 = (size_t)(start + r) * (DIM / 4);
        acc0 += __builtin_nontemporal_load(base + row0);
        acc1 += __builtin_nontemporal_load(base + row0 + 1 * (DIM / 4));
        acc2 += __builtin_nontemporal_load(base + row0 + 2 * (DIM / 4));
        acc3 += __builtin_nontemporal_load(base + row0 + 3 * (DIM / 4));
    }
    for (; r < hi; ++r) {
        acc0 += __builtin_nontemporal_load(base + (size_t)(start + r) * (DIM / 4));
    }
    acc0 += acc1;
    acc2 += acc3;
    acc0 += acc2;

    // ---- Phase 3: combine 4 wave partials in LDS, scale, store ----
    __shared__ f4 s_part[4][64];
    s_part[wv][lane] = acc0;
    __syncthreads();

    if (wv == 0) {
        const f4 a0 = s_part[0][lane];
        const f4 a1 = s_part[1][lane];
        const f4 a2 = s_part[2][lane];
        const f4 a3 = s_part[3][lane];
        const f4 res = (a0 + a1 + a2 + a3) * inv_max;
        __builtin_nontemporal_store(res,
            reinterpret_cast<f4*>(out + (size_t)b * DIM) + lane);
    }
}

extern "C" void kernel_launch(void* const* d_in, const int* in_sizes, int n_in,
                              void* d_out, int out_size, void* d_ws, size_t ws_size,
                              hipStream_t stream) {
    const float* emb = (const float*)d_in[0];
    const int*   len = (const int*)d_in[1];
    float*       out = (float*)d_out;

    graph_mean_kernel<<<BSZ, 256, 0, stream>>>(emb, len, out);
}

// Round 9
// 45.839 us; speedup vs baseline: 1.0935x; 1.0935x over previous
//
#include <hip/hip_runtime.h>

#define BSZ 2048
#define DIM 256
#define NT_CUTOFF 512   // R9 sweep: blocks [0,512) NT (~67 MB), ~201 MB cached.
                        // Curve so far: NT frac 0 -> 48.0us, 1/8 -> 45.9, 1 -> 50.1.

typedef float f4 __attribute__((ext_vector_type(4)));

// One block per graph. 256 threads = 4 waves; all 2048 blocks co-resident.
// R6: contiguous per-wave row streams (1KB sequential per wave) 50->48us.
// R7: NT on first 1/8 of blocks 48->45.9us (partial L3 partition benefit).
// R8: full NT regressed (50.1) — cached fraction's L3 benefit is real but
//     partial; interior minimum in NT fraction. Bisecting at 1/4.
__global__ __launch_bounds__(256) void graph_mean_kernel(
    const float* __restrict__ emb,
    const int*   __restrict__ len,
    float*       __restrict__ out)
{
    const int b    = blockIdx.x;
    const int tid  = threadIdx.x;
    const int lane = tid & 63;
    const int wv   = tid >> 6;

    // ---- Phase 1: offset = sum len[0..b), plus global max(len) ----
    int po = 0, pm = 0;
    #pragma unroll
    for (int j = 0; j < 8; ++j) {
        const int i = tid + j * 256;
        const int l = len[i];
        po += (i < b) ? l : 0;
        pm  = max(pm, l);
    }
    #pragma unroll
    for (int d = 32; d > 0; d >>= 1) {
        po += __shfl_down(po, d);
        pm  = max(pm, __shfl_down(pm, d));
    }
    __shared__ int s_o[4];
    __shared__ int s_m[4];
    if (lane == 0) { s_o[wv] = po; s_m[wv] = pm; }
    __syncthreads();
    const int   start   = s_o[0] + s_o[1] + s_o[2] + s_o[3];
    const float inv_max = 1.0f / (float)max(max(s_m[0], s_m[1]), max(s_m[2], s_m[3]));
    const int   mylen   = len[b];

    // ---- Phase 2: segment sum. Wave wv owns rows [lo, hi) contiguous. ----
    const int lo = (mylen *  wv     ) >> 2;
    const int hi = (mylen * (wv + 1)) >> 2;

    f4 acc0 = {0.f, 0.f, 0.f, 0.f};
    f4 acc1 = {0.f, 0.f, 0.f, 0.f};
    f4 acc2 = {0.f, 0.f, 0.f, 0.f};
    f4 acc3 = {0.f, 0.f, 0.f, 0.f};
    const f4* base = reinterpret_cast<const f4*>(emb) + lane;   // lane = cols lane*4..+3
    int r = lo;
    if (b < NT_CUTOFF) {
        for (; r + 4 <= hi; r += 4) {
            const size_t row0 = (size_t)(start + r) * (DIM / 4);
            acc0 += __builtin_nontemporal_load(base + row0);
            acc1 += __builtin_nontemporal_load(base + row0 + 1 * (DIM / 4));
            acc2 += __builtin_nontemporal_load(base + row0 + 2 * (DIM / 4));
            acc3 += __builtin_nontemporal_load(base + row0 + 3 * (DIM / 4));
        }
        for (; r < hi; ++r) {
            acc0 += __builtin_nontemporal_load(base + (size_t)(start + r) * (DIM / 4));
        }
    } else {
        for (; r + 4 <= hi; r += 4) {
            const size_t row0 = (size_t)(start + r) * (DIM / 4);
            acc0 += base[row0];
            acc1 += base[row0 + 1 * (DIM / 4)];
            acc2 += base[row0 + 2 * (DIM / 4)];
            acc3 += base[row0 + 3 * (DIM / 4)];
        }
        for (; r < hi; ++r) {
            acc0 += base[(size_t)(start + r) * (DIM / 4)];
        }
    }
    acc0 += acc1;
    acc2 += acc3;
    acc0 += acc2;

    // ---- Phase 3: combine 4 wave partials in LDS, scale, store ----
    __shared__ f4 s_part[4][64];
    s_part[wv][lane] = acc0;
    __syncthreads();

    if (wv == 0) {
        const f4 a0 = s_part[0][lane];
        const f4 a1 = s_part[1][lane];
        const f4 a2 = s_part[2][lane];
        const f4 a3 = s_part[3][lane];
        const f4 res = (a0 + a1 + a2 + a3) * inv_max;
        __builtin_nontemporal_store(res,
            reinterpret_cast<f4*>(out + (size_t)b * DIM) + lane);
    }
}

extern "C" void kernel_launch(void* const* d_in, const int* in_sizes, int n_in,
                              void* d_out, int out_size, void* d_ws, size_t ws_size,
                              hipStream_t stream) {
    const float* emb = (const float*)d_in[0];
    const int*   len = (const int*)d_in[1];
    float*       out = (float*)d_out;

    graph_mean_kernel<<<BSZ, 256, 0, stream>>>(emb, len, out);
}